// Round 1
// 330.513 us; speedup vs baseline: 1.0267x; 1.0267x over previous
//
#include <hip/hip_runtime.h>
#include <hip/hip_bf16.h>
#include <math.h>

#define B_  16
#define C_  256
#define T_  4096
#define K_  5

typedef __attribute__((ext_vector_type(4))) float floatx4;
typedef __attribute__((ext_vector_type(8))) short short8;

// ALL tensors f32. CORRECTNESS CONTRACT (verified R7, absmax 0.03125):
//  - offset conv MUST be bit-exact vs the numpy golden: per-tap sequential
//    channel sums (c ascending), separate rounded mul+add (no FMA), taps
//    combined ((d0+d1)+d2), bias last, then pos = f32(t+k-2)+off in one add.
//    Exact-integer pos => both weights 0 (the discontinuity events).
//    The (f,d) chains are INDEPENDENT serial sums -> splitting taps across
//    waves preserves bit-exactness (each chain keeps its c-order).
//  - modulator conv / sigmoid are continuous: any precision/order OK.
//  - k3 may use bf16 MFMA (measured absmax 0.031 << thresholds).

// ---------------- ws layout (bytes) — total 232448 ----------------
// 0       wk1   f32 [3][256][10]   30720   (tap-major: [d][c][f]; f 0..4 offset, 5..9 mod)
// 30720   diagw f32 [256][5]       5120
// 35840   w_r   bf16 [(d*8+m)*8+ch][512]   196608  (A-frags, wave-coalesced)

__global__ __launch_bounds__(256) void k0_setup(
    const float* __restrict__ ow, const float* __restrict__ mw,
    const float* __restrict__ wt, const float* __restrict__ r1w,
    float* __restrict__ wk1, float* __restrict__ diagw,
    __hip_bfloat16* __restrict__ w_r)
{
    int idx = blockIdx.x * 256 + threadIdx.x;
    if (idx < 98304) {
        // w_r[((d*8+m)*8+ch)*512 + ln*32 + cc] = r1w[((m*16+ln)*256 + ch*32+cc)*3 + d]
        // -> a wave's 64 lanes (ln=o%16, qd -> cc=qd*8..+7) read 1 KB contiguous per frag.
        int blk = idx >> 9;          // 0..191
        int r   = idx & 511;
        int ln  = r >> 5;
        int cc  = r & 31;
        int ch  = blk & 7;
        int dm  = blk >> 3;          // 0..23
        int m   = dm & 7;
        int d   = dm >> 3;           // 0..2
        int o   = m * 16 + ln;
        int c   = ch * 32 + cc;
        w_r[idx] = __float2bfloat16(r1w[((size_t)o * 256 + c) * 3 + d]);
    }
    if (idx < 7680) {
        // wk1[(d*256 + c)*10 + f]: contiguous 40B per (d,c) -> one s_load group
        int d = idx / 2560; int rem = idx - d * 2560; int c = rem / 10; int f = rem - c * 10;
        wk1[idx] = (f < 5) ? ow[(f * C_ + c) * 3 + d] : mw[((f - 5) * C_ + c) * 3 + d];
    }
    if (idx < 1280) {
        int c = idx / 5; int k = idx - c * 5;
        diagw[idx] = wt[((size_t)c * C_ + c) * K_ + k];
    }
}

// K12 v3: 64-t tile, 256 threads, grid (64,16) = 1024 blocks -> 4 blocks/CU.
// Phase A: tap-split across waves 0..2 (wave d: 1 load stream + 5 strict
// offset chains + 5 mod FMA chains), 8-deep register prefetch. Wave 3 idles.
// Combine (64 threads): ((d0+d1)+d2)+bias -> pos/floor/ceil/weights (bit-exact).
// Phase B: 4 waves x 64-channel groups, 1-row lookahead gather pipeline.
__global__ __launch_bounds__(256) void k12_fused(
    const float* __restrict__ x,
    const float* __restrict__ wk1,
    const float* __restrict__ ob, const float* __restrict__ mb,
    const float* __restrict__ diagw,
    float* __restrict__ dout)
{
    __shared__ float staps[3][K_][64];
    __shared__ float smod[3][K_][64];
    __shared__ int   spf[K_][64];
    __shared__ int   spc[K_][64];
    __shared__ float swa[K_][64];
    __shared__ float swb[K_][64];
    const int t0  = blockIdx.x * 64;
    const int b   = blockIdx.y;
    const int tid = threadIdx.x;
    const int tl  = tid & 63;
    const int wv  = tid >> 6;
    const int t   = t0 + tl;

    if (wv < 3) {
        const int wvu = __builtin_amdgcn_readfirstlane(wv);
        const int dd  = wvu - 1;                       // tap offset -1/0/+1
        const bool inb = ((unsigned)(t + dd) < (unsigned)T_);
        const float* xp = x + (size_t)b * C_ * T_ + t + (inb ? dd : 0);
        const float* wbase = wk1 + wvu * 2560;         // wave-uniform -> s_load
        float so0=0.f, so1=0.f, so2=0.f, so3=0.f, so4=0.f;   // strict chains
        float am0=0.f, am1=0.f, am2=0.f, am3=0.f, am4=0.f;   // mod partials
        float pv[8];
#pragma unroll
        for (int i = 0; i < 8; ++i) pv[i] = xp[(size_t)i * T_];
        for (int c8 = 0; c8 < 256; c8 += 8) {
            float cv[8];
#pragma unroll
            for (int i = 0; i < 8; ++i) cv[i] = pv[i];
            if (c8 + 8 < 256) {                         // prefetch next 8 channels
                const float* xq = xp + (size_t)(c8 + 8) * T_;
#pragma unroll
                for (int i = 0; i < 8; ++i) pv[i] = xq[(size_t)i * T_];
            }
#pragma unroll
            for (int i = 0; i < 8; ++i) {
                const float v = inb ? cv[i] : 0.f;      // exact zero-pad
                const float* wr_ = wbase + (c8 + i) * 10;
                {
#pragma clang fp contract(off)
                    // strict IEEE f32, c-ascending, separate rounded mul+add
                    float p0 = wr_[0] * v; so0 = so0 + p0;
                    float p1 = wr_[1] * v; so1 = so1 + p1;
                    float p2 = wr_[2] * v; so2 = so2 + p2;
                    float p3 = wr_[3] * v; so3 = so3 + p3;
                    float p4 = wr_[4] * v; so4 = so4 + p4;
                }
                // modulator: continuous path, FMA allowed
                am0 = fmaf(wr_[5], v, am0);
                am1 = fmaf(wr_[6], v, am1);
                am2 = fmaf(wr_[7], v, am2);
                am3 = fmaf(wr_[8], v, am3);
                am4 = fmaf(wr_[9], v, am4);
            }
        }
        staps[wvu][0][tl] = so0; staps[wvu][1][tl] = so1; staps[wvu][2][tl] = so2;
        staps[wvu][3][tl] = so3; staps[wvu][4][tl] = so4;
        smod[wvu][0][tl]  = am0; smod[wvu][1][tl]  = am1; smod[wvu][2][tl]  = am2;
        smod[wvu][3][tl]  = am3; smod[wvu][4][tl]  = am4;
    }
    __syncthreads();

    if (tid < 64) {
#pragma clang fp contract(off)
#pragma unroll
        for (int k = 0; k < K_; ++k) {
            float offv = ((staps[0][k][tl] + staps[1][k][tl]) + staps[2][k][tl]) + ob[k];
            float modv = ((smod[0][k][tl] + smod[1][k][tl]) + smod[2][k][tl]) + mb[k];
            float sig  = 1.f / (1.f + expf(-modv));
            float pos  = (float)(t + k - 2) + offv;   // single f32 add
            pos = fminf(fmaxf(pos, 0.f), 4095.f);
            float pf = floorf(pos), pc = ceilf(pos);
            spf[k][tl] = (int)pf;
            spc[k][tl] = (int)pc;
            swa[k][tl] = (pc - pos) * sig;
            swb[k][tl] = (pos - pf) * sig;
        }
    }
    __syncthreads();

    // ---- phase B: deform gather; thread (cg, tl) covers c in [cg*64, cg*64+64) ----
    const int cgU = __builtin_amdgcn_readfirstlane(wv);   // wave-uniform -> s_load
    int   pfk[K_], pck[K_];
    float ak[K_], bk[K_];
#pragma unroll
    for (int k = 0; k < K_; ++k) {
        pfk[k] = spf[k][tl]; pck[k] = spc[k][tl];
        ak[k]  = swa[k][tl]; bk[k]  = swb[k][tl];
    }
    const float* xr = x    + (size_t)(b * C_ + cgU * 64) * T_;
    float*       dp = dout + (size_t)(b * C_ + cgU * 64) * T_ + t;
    const float* dwp = diagw + cgU * 320;
    float vf[K_], vc[K_];
#pragma unroll
    for (int k = 0; k < K_; ++k) { vf[k] = xr[pfk[k]]; vc[k] = xr[pck[k]]; }
    for (int j = 0; j < 64; ++j) {
        float nf[K_], nc[K_];
        if (j < 63) {                                   // lookahead gathers
            const float* xn = xr + (size_t)(j + 1) * T_;
#pragma unroll
            for (int k = 0; k < K_; ++k) { nf[k] = xn[pfk[k]]; nc[k] = xn[pck[k]]; }
        }
        float accv = 0.f;
#pragma unroll
        for (int k = 0; k < K_; ++k)
            accv += dwp[j * 5 + k] * (vf[k] * ak[k] + vc[k] * bk[k]);
        dp[(size_t)j * T_] = accv;
        if (j < 63) {
#pragma unroll
            for (int k = 0; k < K_; ++k) { vf[k] = nf[k]; vc[k] = nc[k]; }
        }
    }
}

// K3 v3: 64-t tile, grid (64,16) = 1024 blocks, LDS 10.6 KB -> 4 blocks/CU.
// A-frags (weights) straight from L2 (fully coalesced 1 KB/wave loads, no LDS,
// no W barriers). D tile double-buffered: stage ch+1 AFTER MFMA cluster of ch,
// single barrier per chunk -> stage latency overlaps other blocks' MFMAs.
__global__ __launch_bounds__(256) void k3_rp(
    const float* __restrict__ ddef,              // f32 deformed [b][c][t] (d_out)
    const __hip_bfloat16* __restrict__ w_r,      // bf16 A-frag repack (see k0)
    const float* __restrict__ rp1b, const float* __restrict__ rp2w,
    const float* __restrict__ rp2b,
    float* __restrict__ rec)
{
    __shared__ __align__(16) short ld[2][66 * 40];   // [buf][j 66][c 32 stride 40]
    const int t0 = blockIdx.x * 64;
    const int b  = blockIdx.y;
    const int tid  = threadIdx.x;
    const int lane = tid & 63;
    const int w    = tid >> 6;      // wave id = n-tile (16 t)
    const int qd   = lane >> 4;
    const int ln   = lane & 15;
    const short* wsrc = (const short*)w_r;

    floatx4 acc[8];
#pragma unroll
    for (int m = 0; m < 8; ++m) acc[m] = (floatx4){0.f, 0.f, 0.f, 0.f};

    // staging index decomposition (2112 = 32c x 66j elements, 9 per thread)
    int sc[9], sj[9];
#pragma unroll
    for (int i = 0; i < 9; ++i) {
        int f = tid + i * 256;
        sc[i] = f / 66;
        sj[i] = f - sc[i] * 66;
    }
    // prologue: stage chunk 0 -> buf 0
#pragma unroll
    for (int i = 0; i < 9; ++i) {
        int f = tid + i * 256;
        if (f < 2112) {
            int g = t0 - 1 + sj[i];
            float v = ((unsigned)g < (unsigned)T_)
                    ? ddef[(size_t)(b * C_ + sc[i]) * T_ + g] : 0.f;
            __hip_bfloat16 h = __float2bfloat16(v);
            ld[0][sj[i] * 40 + sc[i]] = *(short*)&h;
        }
    }
    __syncthreads();

    for (int ch = 0; ch < 8; ++ch) {
        const int cur = ch & 1;
        // MFMA cluster: 3 ds_read_b128 + 24 coalesced 16B global A-frag loads
#pragma unroll
        for (int d = 0; d < 3; ++d) {
            short8 bfr = *(const short8*)&ld[cur][(w * 16 + ln + d) * 40 + qd * 8];
#pragma unroll
            for (int m = 0; m < 8; ++m) {
                short8 af = *(const short8*)(wsrc
                    + (size_t)(((d * 8 + m) * 8 + ch) * 512 + ln * 32 + qd * 8));
                acc[m] = __builtin_amdgcn_mfma_f32_16x16x32_bf16(af, bfr, acc[m], 0, 0, 0);
            }
        }
        // stage next chunk into the other buffer (reads of cur are done above;
        // writes to cur^1 become visible at the barrier)
        if (ch < 7) {
            const int c0n = (ch + 1) * 32;
#pragma unroll
            for (int i = 0; i < 9; ++i) {
                int f = tid + i * 256;
                if (f < 2112) {
                    int g = t0 - 1 + sj[i];
                    float v = ((unsigned)g < (unsigned)T_)
                            ? ddef[(size_t)(b * C_ + c0n + sc[i]) * T_ + g] : 0.f;
                    __hip_bfloat16 h = __float2bfloat16(v);
                    ld[cur ^ 1][sj[i] * 40 + sc[i]] = *(short*)&h;
                }
            }
        }
        __syncthreads();
    }

    // epilogue (C/D layout: col=ln -> t, row=qd*4+reg -> o)
    float rv = 0.f;
#pragma unroll
    for (int m = 0; m < 8; ++m)
#pragma unroll
        for (int r = 0; r < 4; ++r) {
            int o = m * 16 + qd * 4 + r;
            float h = acc[m][r] + rp1b[o];
            h = h > 0.f ? h : 0.f;
            rv += rp2w[o] * h;
        }
    rv += __shfl_xor(rv, 16);
    rv += __shfl_xor(rv, 32);
    if (qd == 0)
        rec[b * T_ + t0 + w * 16 + ln] = rv + rp2b[0];
}

extern "C" void kernel_launch(void* const* d_in, const int* in_sizes, int n_in,
                              void* d_out, int out_size, void* d_ws, size_t ws_size,
                              hipStream_t stream) {
    const float* x   = (const float*)d_in[0];
    const float* ow  = (const float*)d_in[1];
    const float* ob  = (const float*)d_in[2];
    const float* mw  = (const float*)d_in[3];
    const float* mb  = (const float*)d_in[4];
    const float* wt  = (const float*)d_in[5];
    const float* r1w = (const float*)d_in[6];
    const float* r1b = (const float*)d_in[7];
    const float* r2w = (const float*)d_in[8];
    const float* r2b = (const float*)d_in[9];

    char* ws = (char*)d_ws;
    float*          wk1   = (float*)(ws + 0);
    float*          diagw = (float*)(ws + 30720);
    __hip_bfloat16* w_r   = (__hip_bfloat16*)(ws + 35840);

    float* dout = (float*)d_out;
    float* rec  = (float*)d_out + (size_t)B_ * C_ * T_;

    k0_setup<<<384, 256, 0, stream>>>(ow, mw, wt, r1w, wk1, diagw, w_r);
    k12_fused<<<dim3(T_ / 64, B_), 256, 0, stream>>>(x, wk1, ob, mb, diagw, dout);
    k3_rp<<<dim3(T_ / 64, B_), 256, 0, stream>>>(dout, w_r, r1b, r2w, r2b, rec);
}